// Round 1
// baseline (138.137 us; speedup 1.0000x reference)
//
#include <hip/hip_runtime.h>
#include <math.h>

#define NEXP 8
#define DIM 1024
#define NTOK 32768            // B*S = 8*4096
#define NB 1024               // blocks for main kernel
#define TPB 256               // 4 waves per block
#define WPB 4                 // waves per block
#define NWAVES (NB * WPB)     // 4096
#define EPSF 1e-9f

// ---------------------------------------------------------------------------
// Main kernel: one wave per token (4 tokens batched per iteration).
// logits = x . W^T computed with lane-parallel partial dots, reduced via a
// split butterfly so lane l owns expert (l&7); gumbel+softmax+top2 run
// distributed over 8-lane groups. Per-block loss partials -> d_ws.
// ---------------------------------------------------------------------------
__global__ __launch_bounds__(TPB) void gate_kernel(
    const float* __restrict__ x, const float* __restrict__ W,
    const float* __restrict__ noise, float* __restrict__ out,
    float* __restrict__ partials)
{
    __shared__ float4 Wlds[NEXP * DIM / 4];   // 2048 float4 = 32 KB
    __shared__ float bpart[WPB][16];

    const int tid  = threadIdx.x;
    const int lane = tid & 63;
    const int wid  = tid >> 6;
    const int e_own = lane & 7;

    // stage W (32 KB) into LDS
    const float4* Wg = (const float4*)W;
    #pragma unroll
    for (int i = 0; i < (NEXP * DIM / 4) / TPB; ++i)
        Wlds[tid + i * TPB] = Wg[tid + i * TPB];
    __syncthreads();

    float ls = 0.f, lq = 0.f;   // per-lane loss partials (x8 duplicated)

    const int gw = blockIdx.x * WPB + wid;
    for (int qi = gw; qi < NTOK / 4; qi += NWAVES) {
        const int t0 = qi * 4;

        float acc[4][NEXP];
        #pragma unroll
        for (int j = 0; j < 4; ++j)
            #pragma unroll
            for (int e = 0; e < NEXP; ++e) acc[j][e] = 0.f;

        #pragma unroll
        for (int p = 0; p < 4; ++p) {
            float4 xv[4];
            #pragma unroll
            for (int j = 0; j < 4; ++j)
                xv[j] = *(const float4*)(x + (size_t)(t0 + j) * DIM + p * 256 + (lane << 2));
            #pragma unroll
            for (int e = 0; e < NEXP; ++e) {
                float4 wv = Wlds[e * 256 + p * 64 + lane];
                #pragma unroll
                for (int j = 0; j < 4; ++j)
                    acc[j][e] += xv[j].x * wv.x + xv[j].y * wv.y
                               + xv[j].z * wv.z + xv[j].w * wv.w;
            }
        }

        #pragma unroll
        for (int j = 0; j < 4; ++j) {
            const int t = t0 + j;

            // ---- split butterfly: 8 partials over 64 lanes -> lane owns e=l&7
            float keep4[4];
            {
                const int p0 = lane & 1;
                #pragma unroll
                for (int k = 0; k < 4; ++k) {
                    float g = acc[j][2 * k + (1 - p0)];
                    keep4[k] = acc[j][2 * k + p0] + __shfl_xor(g, 1);
                }
            }
            float keep2[2];
            {
                const int q = (lane >> 1) & 1;
                #pragma unroll
                for (int k = 0; k < 2; ++k) {
                    float g = keep4[2 * k + (1 - q)];
                    keep2[k] = keep4[2 * k + q] + __shfl_xor(g, 2);
                }
            }
            float z;
            {
                const int r = (lane >> 2) & 1;
                float g = keep2[1 - r];
                z = keep2[r] + __shfl_xor(g, 4);
            }
            z += __shfl_xor(z, 8);
            z += __shfl_xor(z, 16);
            z += __shfl_xor(z, 32);
            // z = logit of expert e_own (replicated across the 8 groups)

            // ---- gumbel noise
            float n = noise[(size_t)t * NEXP + e_own];
            float gum = -logf(-logf(n + EPSF) + EPSF);
            z += gum;

            // ---- softmax over the 8-lane group
            float m = z;
            m = fmaxf(m, __shfl_xor(m, 1));
            m = fmaxf(m, __shfl_xor(m, 2));
            m = fmaxf(m, __shfl_xor(m, 4));
            float ex = expf(z - m);
            float sm = ex;
            sm += __shfl_xor(sm, 1);
            sm += __shfl_xor(sm, 2);
            sm += __shfl_xor(sm, 4);
            float score = ex / sm;

            // ---- top-2 within the 8-lane group (value desc, index asc on tie)
            float b1v = score; int b1i = e_own;
            float b2v = -1.f;  int b2i = -1;
            #pragma unroll
            for (int d = 1; d < 8; d <<= 1) {
                float p1v = __shfl_xor(b1v, d); int p1i = __shfl_xor(b1i, d);
                float p2v = __shfl_xor(b2v, d); int p2i = __shfl_xor(b2i, d);
                if (p1v > b1v || (p1v == b1v && p1i < b1i)) {
                    b2v = b1v; b2i = b1i;
                    b1v = p1v; b1i = p1i;
                } else if (p1v > b2v || (p1v == b2v && p1i < b2i)) {
                    b2v = p1v; b2i = p1i;
                }
                if (p2v > b2v || (p2v == b2v && p2i < b2i)) {
                    b2v = p2v; b2i = p2i;
                }
            }

            // ---- write dispatch mask row (9 floats)
            float mask = (e_own == b1i) ? b1v : ((e_own == b2i) ? b2v : 0.f);
            if (lane < 8)
                out[(size_t)t * 9 + 1 + lane] = mask;
            else if (lane == 8)
                out[(size_t)t * 9] = 1.0f;

            // ---- loss accumulation (each lane: its owned expert's score)
            ls += score;
            lq += score * score;
        }
    }

    // reduce the 8 duplicated groups within the wave (result = 8x true sum)
    ls += __shfl_xor(ls, 8); ls += __shfl_xor(ls, 16); ls += __shfl_xor(ls, 32);
    lq += __shfl_xor(lq, 8); lq += __shfl_xor(lq, 16); lq += __shfl_xor(lq, 32);

    if (lane < 8) { bpart[wid][e_own] = ls; bpart[wid][8 + e_own] = lq; }
    __syncthreads();
    if (tid < 16) {
        float s = 0.f;
        #pragma unroll
        for (int w = 0; w < WPB; ++w) s += bpart[w][tid];
        partials[blockIdx.x * 16 + tid] = s;
    }
}

// ---------------------------------------------------------------------------
// Finalize: reduce NB x 16 partials -> load balance loss at out[NTOK*9]
// ---------------------------------------------------------------------------
__global__ __launch_bounds__(256) void finalize_kernel(
    const float* __restrict__ partials, float* __restrict__ out)
{
    __shared__ float sdata[256];
    const int tid = threadIdx.x;
    const int v = tid & 15, row = tid >> 4;
    float s = 0.f;
    for (int b = row; b < NB; b += 16) s += partials[b * 16 + v];
    sdata[tid] = s;
    __syncthreads();
    if (tid < 16) {
        float tot = 0.f;
        #pragma unroll
        for (int r = 0; r < 16; ++r) tot += sdata[r * 16 + tid];
        sdata[tid] = tot;   // safe: only sdata[i] read by thread i before write
    }
    __syncthreads();
    if (tid == 0) {
        const float invN = 1.0f / (8.0f * (float)NTOK);  // /8: duplicated groups
        float loss = 0.f;
        #pragma unroll
        for (int e = 0; e < NEXP; ++e)
            loss += (sdata[e] * invN) * (sdata[8 + e] * invN);
        out[(size_t)NTOK * 9] = loss * 64.0f;            // * E^2
    }
}

extern "C" void kernel_launch(void* const* d_in, const int* in_sizes, int n_in,
                              void* d_out, int out_size, void* d_ws, size_t ws_size,
                              hipStream_t stream) {
    const float* x     = (const float*)d_in[0];
    const float* W     = (const float*)d_in[1];
    const float* noise = (const float*)d_in[2];
    float* out = (float*)d_out;
    float* partials = (float*)d_ws;   // NB*16 floats = 64 KB

    gate_kernel<<<NB, TPB, 0, stream>>>(x, W, noise, out, partials);
    finalize_kernel<<<1, 256, 0, stream>>>(partials, out);
}

// Round 3
// 70.467 us; speedup vs baseline: 1.9603x; 1.9603x over previous
//
#include <hip/hip_runtime.h>
#include <math.h>

#define NEXP 8
#define DIM 1024
#define NTOK 32768            // B*S = 8*4096
#define EPSF 1e-9f

#define K1_NB 2048            // 2048 blocks x 4 waves x 4 tokens = 32768
#define K2_NB 512             // 512 blocks x 64 threads = 32768 tokens

// ---------------------------------------------------------------------------
// K1: logits. W (32 KB) staged in LDS once per block; each wave computes 4
// tokens' 8 logits via p=0..3 column chunks (lane covers cols p*256+4l..+3).
// Split butterfly leaves lane l with the logit of expert (l&7), replicated
// across the eight 8-lane groups; lanes 0..31 park 4 tokens x 8 logits in
// out[t*9+1..8] (K2 reads them back in place).
// ---------------------------------------------------------------------------
__global__ __launch_bounds__(256) void logits_kernel(
    const float* __restrict__ x, const float* __restrict__ W,
    float* __restrict__ out)
{
    __shared__ float4 Wlds[NEXP * DIM / 4];   // 2048 float4 = 32 KB

    const int tid  = threadIdx.x;
    const int lane = tid & 63;
    const int wid  = tid >> 6;

    const float4* Wg = (const float4*)W;
    #pragma unroll
    for (int i = 0; i < (NEXP * DIM / 4) / 256; ++i)
        Wlds[tid + i * 256] = Wg[tid + i * 256];
    __syncthreads();

    const int gw = (blockIdx.x << 2) + wid;   // wave id 0..8191
    const int t0 = gw << 2;

    float acc[4][NEXP];
    #pragma unroll
    for (int j = 0; j < 4; ++j)
        #pragma unroll
        for (int e = 0; e < NEXP; ++e) acc[j][e] = 0.f;

    #pragma unroll
    for (int p = 0; p < 4; ++p) {
        float4 xv[4];
        #pragma unroll
        for (int j = 0; j < 4; ++j)
            xv[j] = *(const float4*)(x + (size_t)(t0 + j) * DIM + p * 256 + (lane << 2));
        #pragma unroll
        for (int e = 0; e < NEXP; ++e) {
            float4 wv = Wlds[e * 256 + p * 64 + lane];
            #pragma unroll
            for (int j = 0; j < 4; ++j)
                acc[j][e] += xv[j].x * wv.x + xv[j].y * wv.y
                           + xv[j].z * wv.z + xv[j].w * wv.w;
        }
    }

    const bool p0 = lane & 1;
    const bool p1 = (lane >> 1) & 1;
    const bool p2 = (lane >> 2) & 1;

    // level 1 (xor 1): 8 -> 4 partials (all tokens' shuffles independent)
    float k4[4][4];
    #pragma unroll
    for (int j = 0; j < 4; ++j)
        #pragma unroll
        for (int k = 0; k < 4; ++k) {
            float a = acc[j][2 * k], b = acc[j][2 * k + 1];
            float keep = p0 ? b : a, give = p0 ? a : b;
            k4[j][k] = keep + __shfl_xor(give, 1);
        }
    // level 2 (xor 2): 4 -> 2
    float k2v[4][2];
    #pragma unroll
    for (int j = 0; j < 4; ++j)
        #pragma unroll
        for (int k = 0; k < 2; ++k) {
            float a = k4[j][2 * k], b = k4[j][2 * k + 1];
            float keep = p1 ? b : a, give = p1 ? a : b;
            k2v[j][k] = keep + __shfl_xor(give, 2);
        }
    // level 3 (xor 4): 2 -> 1
    float z[4];
    #pragma unroll
    for (int j = 0; j < 4; ++j) {
        float a = k2v[j][0], b = k2v[j][1];
        float keep = p2 ? b : a, give = p2 ? a : b;
        z[j] = keep + __shfl_xor(give, 4);
    }
    // levels 4-6: sum the eight 8-lane groups
    #pragma unroll
    for (int j = 0; j < 4; ++j) {
        z[j] += __shfl_xor(z[j], 8);
        z[j] += __shfl_xor(z[j], 16);
        z[j] += __shfl_xor(z[j], 32);
    }

    if (lane < 32) {
        int j = lane >> 3, e = lane & 7;
        float zz = (j == 0) ? z[0] : (j == 1) ? z[1] : (j == 2) ? z[2] : z[3];
        out[(size_t)(t0 + j) * 9 + 1 + e] = zz;
    }
}

// ---------------------------------------------------------------------------
// K2: one thread per token. Reads the 8 logits K1 parked in out[t*9+1..8],
// gumbel + softmax + top-2 fully in registers, overwrites the row.
// Loss partials: 16 ILP butterflies across the wave; lane 0 writes 16 floats.
// ---------------------------------------------------------------------------
__global__ __launch_bounds__(64) void epilogue_kernel(
    const float* __restrict__ noise, float* __restrict__ out,
    float* __restrict__ partials)
{
    const int lane = threadIdx.x;
    const int t = blockIdx.x * 64 + lane;

    float z[NEXP];
    #pragma unroll
    for (int e = 0; e < NEXP; ++e)
        z[e] = out[(size_t)t * 9 + 1 + e];

    float4 n0 = *(const float4*)(noise + (size_t)t * NEXP);
    float4 n1 = *(const float4*)(noise + (size_t)t * NEXP + 4);
    float nv[NEXP] = {n0.x, n0.y, n0.z, n0.w, n1.x, n1.y, n1.z, n1.w};

    #pragma unroll
    for (int e = 0; e < NEXP; ++e)
        z[e] += -logf(-logf(nv[e] + EPSF) + EPSF);

    float m = z[0];
    #pragma unroll
    for (int e = 1; e < NEXP; ++e) m = fmaxf(m, z[e]);

    float sc[NEXP], s = 0.f;
    #pragma unroll
    for (int e = 0; e < NEXP; ++e) { sc[e] = expf(z[e] - m); s += sc[e]; }
    float inv = 1.0f / s;
    #pragma unroll
    for (int e = 0; e < NEXP; ++e) sc[e] *= inv;

    // top-2 scan (value desc, earliest index wins on ties — matches lax.top_k)
    float b1v = sc[0]; int b1i = 0;
    float b2v = -1.f;  int b2i = -1;
    #pragma unroll
    for (int e = 1; e < NEXP; ++e) {
        if (sc[e] > b1v)      { b2v = b1v; b2i = b1i; b1v = sc[e]; b1i = e; }
        else if (sc[e] > b2v) { b2v = sc[e]; b2i = e; }
    }

    out[(size_t)t * 9] = 1.0f;
    #pragma unroll
    for (int e = 0; e < NEXP; ++e)
        out[(size_t)t * 9 + 1 + e] = (e == b1i) ? b1v : (e == b2i) ? b2v : 0.f;

    // loss partials: v[0..7] = sum sc, v[8..15] = sum sc^2 over the wave
    float v[16];
    #pragma unroll
    for (int e = 0; e < NEXP; ++e) { v[e] = sc[e]; v[8 + e] = sc[e] * sc[e]; }
    #pragma unroll
    for (int d = 1; d < 64; d <<= 1)
        #pragma unroll
        for (int k = 0; k < 16; ++k)
            v[k] += __shfl_xor(v[k], d);

    if (lane == 0) {
        #pragma unroll
        for (int k = 0; k < 16; ++k)
            partials[blockIdx.x * 16 + k] = v[k];
    }
}

// ---------------------------------------------------------------------------
// K3: finalize loss at out[NTOK*9] from K2_NB x 16 partials (deterministic)
// ---------------------------------------------------------------------------
__global__ __launch_bounds__(64) void finalize_kernel(
    const float* __restrict__ partials, float* __restrict__ out)
{
    const int lane = threadIdx.x;
    const int v = lane & 15, rg = lane >> 4;   // 4 row-groups

    float s = 0.f;
    for (int b = rg; b < K2_NB; b += 4)
        s += partials[b * 16 + v];
    s += __shfl_xor(s, 16);
    s += __shfl_xor(s, 32);
    // lanes 0..15 now hold totals for the 16 stats

    const float invN = 1.0f / (float)NTOK;
    float partner = __shfl_xor(s, 8);          // lane e<8: sum of squares
    float prod = (s * invN) * (partner * invN);
    prod += __shfl_xor(prod, 1);
    prod += __shfl_xor(prod, 2);
    prod += __shfl_xor(prod, 4);
    if (lane == 0)
        out[(size_t)NTOK * 9] = prod * 64.0f;  // * E^2
}

extern "C" void kernel_launch(void* const* d_in, const int* in_sizes, int n_in,
                              void* d_out, int out_size, void* d_ws, size_t ws_size,
                              hipStream_t stream) {
    const float* x     = (const float*)d_in[0];
    const float* W     = (const float*)d_in[1];
    const float* noise = (const float*)d_in[2];
    float* out = (float*)d_out;
    float* partials = (float*)d_ws;   // 512*16 floats = 32 KB

    logits_kernel<<<K1_NB, 256, 0, stream>>>(x, W, out);
    epilogue_kernel<<<K2_NB, 64, 0, stream>>>(noise, out, partials);
    finalize_kernel<<<1, 64, 0, stream>>>(partials, out);
}

// Round 4
// 41.811 us; speedup vs baseline: 3.3038x; 1.6854x over previous
//
#include <hip/hip_runtime.h>
#include <math.h>

#define NEXP 8
#define DIM 1024
#define NTOK 32768            // B*S = 8*4096
#define EPSF 1e-9f

#define K1_NB 2048            // 2048 blocks x 4 waves x 4 tokens = 32768
#define K2_NB 128             // 128 blocks x 256 threads = 32768 tokens

// ---------------------------------------------------------------------------
// K1: logits. W (32 KB) staged in LDS once per block; each wave computes 4
// tokens' 8 logits via p=0..3 column chunks (lane covers cols p*256+4l..+3).
// Split butterfly leaves lane l with the logit of expert (l&7), replicated
// across the eight 8-lane groups; lanes 0..31 park 4 tokens x 8 logits in
// out[t*9+1..8] (K2 reads them back in place).
// ---------------------------------------------------------------------------
__global__ __launch_bounds__(256) void logits_kernel(
    const float* __restrict__ x, const float* __restrict__ W,
    float* __restrict__ out)
{
    __shared__ float4 Wlds[NEXP * DIM / 4];   // 2048 float4 = 32 KB

    const int tid  = threadIdx.x;
    const int lane = tid & 63;
    const int wid  = tid >> 6;

    const float4* Wg = (const float4*)W;
    #pragma unroll
    for (int i = 0; i < (NEXP * DIM / 4) / 256; ++i)
        Wlds[tid + i * 256] = Wg[tid + i * 256];
    __syncthreads();

    const int gw = (blockIdx.x << 2) + wid;   // wave id 0..8191
    const int t0 = gw << 2;

    float acc[4][NEXP];
    #pragma unroll
    for (int j = 0; j < 4; ++j)
        #pragma unroll
        for (int e = 0; e < NEXP; ++e) acc[j][e] = 0.f;

    #pragma unroll
    for (int p = 0; p < 4; ++p) {
        float4 xv[4];
        #pragma unroll
        for (int j = 0; j < 4; ++j)
            xv[j] = *(const float4*)(x + (size_t)(t0 + j) * DIM + p * 256 + (lane << 2));
        #pragma unroll
        for (int e = 0; e < NEXP; ++e) {
            float4 wv = Wlds[e * 256 + p * 64 + lane];
            #pragma unroll
            for (int j = 0; j < 4; ++j)
                acc[j][e] += xv[j].x * wv.x + xv[j].y * wv.y
                           + xv[j].z * wv.z + xv[j].w * wv.w;
        }
    }

    const bool p0 = lane & 1;
    const bool p1 = (lane >> 1) & 1;
    const bool p2 = (lane >> 2) & 1;

    // level 1 (xor 1): 8 -> 4 partials (all tokens' shuffles independent)
    float k4[4][4];
    #pragma unroll
    for (int j = 0; j < 4; ++j)
        #pragma unroll
        for (int k = 0; k < 4; ++k) {
            float a = acc[j][2 * k], b = acc[j][2 * k + 1];
            float keep = p0 ? b : a, give = p0 ? a : b;
            k4[j][k] = keep + __shfl_xor(give, 1);
        }
    // level 2 (xor 2): 4 -> 2
    float k2v[4][2];
    #pragma unroll
    for (int j = 0; j < 4; ++j)
        #pragma unroll
        for (int k = 0; k < 2; ++k) {
            float a = k4[j][2 * k], b = k4[j][2 * k + 1];
            float keep = p1 ? b : a, give = p1 ? a : b;
            k2v[j][k] = keep + __shfl_xor(give, 2);
        }
    // level 3 (xor 4): 2 -> 1
    float z[4];
    #pragma unroll
    for (int j = 0; j < 4; ++j) {
        float a = k2v[j][0], b = k2v[j][1];
        float keep = p2 ? b : a, give = p2 ? a : b;
        z[j] = keep + __shfl_xor(give, 4);
    }
    // levels 4-6: sum the eight 8-lane groups
    #pragma unroll
    for (int j = 0; j < 4; ++j) {
        z[j] += __shfl_xor(z[j], 8);
        z[j] += __shfl_xor(z[j], 16);
        z[j] += __shfl_xor(z[j], 32);
    }

    if (lane < 32) {
        int j = lane >> 3, e = lane & 7;
        float zz = (j == 0) ? z[0] : (j == 1) ? z[1] : (j == 2) ? z[2] : z[3];
        out[(size_t)(t0 + j) * 9 + 1 + e] = zz;
    }
}

// ---------------------------------------------------------------------------
// K2: one thread per token (128 blocks x 256). Reads the 8 logits K1 parked
// in out[t*9+1..8], gumbel + softmax + top-2 fully in registers, overwrites
// the row. Loss partials: 16-stat wave butterfly + cross-wave LDS reduce ->
// partials[block][16] (only 128 rows now).
// ---------------------------------------------------------------------------
__global__ __launch_bounds__(256) void epilogue_kernel(
    const float* __restrict__ noise, float* __restrict__ out,
    float* __restrict__ partials)
{
    __shared__ float wsum[4][16];

    const int tid  = threadIdx.x;
    const int lane = tid & 63;
    const int wid  = tid >> 6;
    const int t = blockIdx.x * 256 + tid;

    float z[NEXP];
    #pragma unroll
    for (int e = 0; e < NEXP; ++e)
        z[e] = out[(size_t)t * 9 + 1 + e];

    float4 n0 = *(const float4*)(noise + (size_t)t * NEXP);
    float4 n1 = *(const float4*)(noise + (size_t)t * NEXP + 4);
    float nv[NEXP] = {n0.x, n0.y, n0.z, n0.w, n1.x, n1.y, n1.z, n1.w};

    #pragma unroll
    for (int e = 0; e < NEXP; ++e)
        z[e] += -logf(-logf(nv[e] + EPSF) + EPSF);

    float m = z[0];
    #pragma unroll
    for (int e = 1; e < NEXP; ++e) m = fmaxf(m, z[e]);

    float sc[NEXP], s = 0.f;
    #pragma unroll
    for (int e = 0; e < NEXP; ++e) { sc[e] = expf(z[e] - m); s += sc[e]; }
    float inv = 1.0f / s;
    #pragma unroll
    for (int e = 0; e < NEXP; ++e) sc[e] *= inv;

    // top-2 scan (value desc, earliest index wins on ties — matches lax.top_k)
    float b1v = sc[0]; int b1i = 0;
    float b2v = -1.f;  int b2i = -1;
    #pragma unroll
    for (int e = 1; e < NEXP; ++e) {
        if (sc[e] > b1v)      { b2v = b1v; b2i = b1i; b1v = sc[e]; b1i = e; }
        else if (sc[e] > b2v) { b2v = sc[e]; b2i = e; }
    }

    out[(size_t)t * 9] = 1.0f;
    #pragma unroll
    for (int e = 0; e < NEXP; ++e)
        out[(size_t)t * 9 + 1 + e] = (e == b1i) ? b1v : (e == b2i) ? b2v : 0.f;

    // loss partials: v[0..7] = sum sc, v[8..15] = sum sc^2 over the wave
    float v[16];
    #pragma unroll
    for (int e = 0; e < NEXP; ++e) { v[e] = sc[e]; v[8 + e] = sc[e] * sc[e]; }
    #pragma unroll
    for (int d = 1; d < 64; d <<= 1)
        #pragma unroll
        for (int k = 0; k < 16; ++k)
            v[k] += __shfl_xor(v[k], d);

    if (lane == 0) {
        #pragma unroll
        for (int k = 0; k < 16; ++k) wsum[wid][k] = v[k];
    }
    __syncthreads();
    if (tid < 16) {
        float s4 = 0.f;
        #pragma unroll
        for (int w = 0; w < 4; ++w) s4 += wsum[w][tid];
        partials[blockIdx.x * 16 + tid] = s4;
    }
}

// ---------------------------------------------------------------------------
// K3: finalize loss at out[NTOK*9] from 128 x 16 partials. One wave; each
// lane (v = lane&15, rg = lane>>4) sums 32 rows with a fully unrolled loop
// (all loads independent -> pipelined), then shuffle-reduce.
// ---------------------------------------------------------------------------
__global__ __launch_bounds__(64) void finalize_kernel(
    const float* __restrict__ partials, float* __restrict__ out)
{
    const int lane = threadIdx.x;
    const int v = lane & 15, rg = lane >> 4;   // 4 row-groups

    float s = 0.f;
    #pragma unroll
    for (int b = 0; b < K2_NB / 4; ++b)        // 32 independent loads
        s += partials[(b * 4 + rg) * 16 + v];
    s += __shfl_xor(s, 16);
    s += __shfl_xor(s, 32);
    // lanes 0..15 hold totals for the 16 stats

    const float invN = 1.0f / (float)NTOK;
    float partner = __shfl_xor(s, 8);          // lane e<8: pairs sum <-> sumsq
    float prod = (s * invN) * (partner * invN);
    prod += __shfl_xor(prod, 1);
    prod += __shfl_xor(prod, 2);
    prod += __shfl_xor(prod, 4);
    if (lane == 0)
        out[(size_t)NTOK * 9] = prod * 64.0f;  // * E^2
}

extern "C" void kernel_launch(void* const* d_in, const int* in_sizes, int n_in,
                              void* d_out, int out_size, void* d_ws, size_t ws_size,
                              hipStream_t stream) {
    const float* x     = (const float*)d_in[0];
    const float* W     = (const float*)d_in[1];
    const float* noise = (const float*)d_in[2];
    float* out = (float*)d_out;
    float* partials = (float*)d_ws;   // 128*16 floats = 8 KB

    logits_kernel<<<K1_NB, 256, 0, stream>>>(x, W, out);
    epilogue_kernel<<<K2_NB, 256, 0, stream>>>(noise, out, partials);
    finalize_kernel<<<1, 64, 0, stream>>>(partials, out);
}

// Round 5
// 36.499 us; speedup vs baseline: 3.7847x; 1.1455x over previous
//
#include <hip/hip_runtime.h>
#include <math.h>

#define NEXP 8
#define DIM 1024
#define NTOK 32768            // B*S = 8*4096
#define EPSF 1e-9f

#define K1_NB 2048            // 2048 blocks x 4 waves x 4 tokens = 32768
#define K2_NB 512             // 512 blocks x 64 threads = 32768 tokens

// ---------------------------------------------------------------------------
// K1: logits. W (32 KB) staged in LDS once per block. Each wave computes 4
// tokens' 8 logits in TWO halves of 2 tokens (keeps live VGPRs ~90 so the
// __launch_bounds__(256,4) cap of 128 VGPR holds without spills ->
// 4 blocks/CU, 16 waves/CU). Per half: 8 x-loads in flight, 32 LDS W-reads,
// split butterfly leaves lane l with logit of expert (l&7) for both tokens
// (replicated across the eight 8-lane groups); lanes 0..15 park 2 tokens x 8
// logits in out[t*9+1..8] (K2 reads them back in place).
// ---------------------------------------------------------------------------
__global__ __launch_bounds__(256, 4) void logits_kernel(
    const float* __restrict__ x, const float* __restrict__ W,
    float* __restrict__ out)
{
    __shared__ float4 Wlds[NEXP * DIM / 4];   // 2048 float4 = 32 KB

    const int tid  = threadIdx.x;
    const int lane = tid & 63;
    const int wid  = tid >> 6;

    const float4* Wg = (const float4*)W;
    #pragma unroll
    for (int i = 0; i < (NEXP * DIM / 4) / 256; ++i)
        Wlds[tid + i * 256] = Wg[tid + i * 256];
    __syncthreads();

    const int gw = (blockIdx.x << 2) + wid;   // wave id 0..8191
    const int t0 = gw << 2;

    const bool p0 = lane & 1;
    const bool p1 = (lane >> 1) & 1;
    const bool p2 = (lane >> 2) & 1;

    #pragma unroll
    for (int half = 0; half < 2; ++half) {
        const int ta = t0 + half * 2;

        // 8 independent x-loads (2 tokens x 4 chunks)
        float4 xv[2][4];
        #pragma unroll
        for (int j = 0; j < 2; ++j)
            #pragma unroll
            for (int p = 0; p < 4; ++p)
                xv[j][p] = *(const float4*)(x + (size_t)(ta + j) * DIM + p * 256 + (lane << 2));

        float acc[2][NEXP];
        #pragma unroll
        for (int j = 0; j < 2; ++j)
            #pragma unroll
            for (int e = 0; e < NEXP; ++e) acc[j][e] = 0.f;

        #pragma unroll
        for (int p = 0; p < 4; ++p)
            #pragma unroll
            for (int e = 0; e < NEXP; ++e) {
                float4 wv = Wlds[e * 256 + p * 64 + lane];
                #pragma unroll
                for (int j = 0; j < 2; ++j)
                    acc[j][e] += xv[j][p].x * wv.x + xv[j][p].y * wv.y
                               + xv[j][p].z * wv.z + xv[j][p].w * wv.w;
            }

        // split butterfly: 8 partials -> lane owns expert (lane&7)
        float k4[2][4];
        #pragma unroll
        for (int j = 0; j < 2; ++j)
            #pragma unroll
            for (int k = 0; k < 4; ++k) {
                float a = acc[j][2 * k], b = acc[j][2 * k + 1];
                float keep = p0 ? b : a, give = p0 ? a : b;
                k4[j][k] = keep + __shfl_xor(give, 1);
            }
        float k2v[2][2];
        #pragma unroll
        for (int j = 0; j < 2; ++j)
            #pragma unroll
            for (int k = 0; k < 2; ++k) {
                float a = k4[j][2 * k], b = k4[j][2 * k + 1];
                float keep = p1 ? b : a, give = p1 ? a : b;
                k2v[j][k] = keep + __shfl_xor(give, 2);
            }
        float z[2];
        #pragma unroll
        for (int j = 0; j < 2; ++j) {
            float a = k2v[j][0], b = k2v[j][1];
            float keep = p2 ? b : a, give = p2 ? a : b;
            z[j] = keep + __shfl_xor(give, 4);
        }
        #pragma unroll
        for (int j = 0; j < 2; ++j) {
            z[j] += __shfl_xor(z[j], 8);
            z[j] += __shfl_xor(z[j], 16);
            z[j] += __shfl_xor(z[j], 32);
        }

        if (lane < 16) {
            int j = lane >> 3, e = lane & 7;
            out[(size_t)(ta + j) * 9 + 1 + e] = j ? z[1] : z[0];
        }
    }
}

// ---------------------------------------------------------------------------
// K2: one thread per token (512 blocks x 64 -> 2 blocks/CU on all CUs).
// Reads the 8 logits K1 parked in out[t*9+1..8], gumbel + softmax + top-2
// fully in registers, overwrites the row. Loss partials: 16-stat wave
// butterfly; lane 0 writes partials[block][16].
// ---------------------------------------------------------------------------
__global__ __launch_bounds__(64) void epilogue_kernel(
    const float* __restrict__ noise, float* __restrict__ out,
    float* __restrict__ partials)
{
    const int lane = threadIdx.x;
    const int t = blockIdx.x * 64 + lane;

    float z[NEXP];
    #pragma unroll
    for (int e = 0; e < NEXP; ++e)
        z[e] = out[(size_t)t * 9 + 1 + e];

    float4 n0 = *(const float4*)(noise + (size_t)t * NEXP);
    float4 n1 = *(const float4*)(noise + (size_t)t * NEXP + 4);
    float nv[NEXP] = {n0.x, n0.y, n0.z, n0.w, n1.x, n1.y, n1.z, n1.w};

    #pragma unroll
    for (int e = 0; e < NEXP; ++e)
        z[e] += -logf(-logf(nv[e] + EPSF) + EPSF);

    float m = z[0];
    #pragma unroll
    for (int e = 1; e < NEXP; ++e) m = fmaxf(m, z[e]);

    float sc[NEXP], s = 0.f;
    #pragma unroll
    for (int e = 0; e < NEXP; ++e) { sc[e] = expf(z[e] - m); s += sc[e]; }
    float inv = 1.0f / s;
    #pragma unroll
    for (int e = 0; e < NEXP; ++e) sc[e] *= inv;

    // top-2 scan (value desc, earliest index wins on ties — matches lax.top_k)
    float b1v = sc[0]; int b1i = 0;
    float b2v = -1.f;  int b2i = -1;
    #pragma unroll
    for (int e = 1; e < NEXP; ++e) {
        if (sc[e] > b1v)      { b2v = b1v; b2i = b1i; b1v = sc[e]; b1i = e; }
        else if (sc[e] > b2v) { b2v = sc[e]; b2i = e; }
    }

    out[(size_t)t * 9] = 1.0f;
    #pragma unroll
    for (int e = 0; e < NEXP; ++e)
        out[(size_t)t * 9 + 1 + e] = (e == b1i) ? b1v : (e == b2i) ? b2v : 0.f;

    // loss partials: v[0..7] = sum sc, v[8..15] = sum sc^2 over the wave
    float v[16];
    #pragma unroll
    for (int e = 0; e < NEXP; ++e) { v[e] = sc[e]; v[8 + e] = sc[e] * sc[e]; }
    #pragma unroll
    for (int d = 1; d < 64; d <<= 1)
        #pragma unroll
        for (int k = 0; k < 16; ++k)
            v[k] += __shfl_xor(v[k], d);

    if (lane == 0) {
        #pragma unroll
        for (int k = 0; k < 16; ++k)
            partials[blockIdx.x * 16 + k] = v[k];
    }
}

// ---------------------------------------------------------------------------
// K3: finalize loss at out[NTOK*9] from 512 x 16 partials. One wave; lane
// (v = lane&15, rg = lane>>4) sums 128 rows via 128 fully-unrolled
// independent loads feeding 4 accumulator chains, then shuffle-reduce.
// ---------------------------------------------------------------------------
__global__ __launch_bounds__(64) void finalize_kernel(
    const float* __restrict__ partials, float* __restrict__ out)
{
    const int lane = threadIdx.x;
    const int v = lane & 15, rg = lane >> 4;   // 4 row-groups

    float a4[4] = {0.f, 0.f, 0.f, 0.f};
    #pragma unroll
    for (int i = 0; i < K2_NB / 16; ++i)       // 32 iters x 4 chains = 128 loads
        #pragma unroll
        for (int q = 0; q < 4; ++q)
            a4[q] += partials[((i * 4 + q) * 4 + rg) * 16 + v];
    float s = (a4[0] + a4[1]) + (a4[2] + a4[3]);

    s += __shfl_xor(s, 16);
    s += __shfl_xor(s, 32);
    // lanes 0..15 hold totals for the 16 stats

    const float invN = 1.0f / (float)NTOK;
    float partner = __shfl_xor(s, 8);          // pairs sum <-> sumsq
    float prod = (s * invN) * (partner * invN);
    prod += __shfl_xor(prod, 1);
    prod += __shfl_xor(prod, 2);
    prod += __shfl_xor(prod, 4);
    if (lane == 0)
        out[(size_t)NTOK * 9] = prod * 64.0f;  // * E^2
}

extern "C" void kernel_launch(void* const* d_in, const int* in_sizes, int n_in,
                              void* d_out, int out_size, void* d_ws, size_t ws_size,
                              hipStream_t stream) {
    const float* x     = (const float*)d_in[0];
    const float* W     = (const float*)d_in[1];
    const float* noise = (const float*)d_in[2];
    float* out = (float*)d_out;
    float* partials = (float*)d_ws;   // 512*16 floats = 32 KB

    logits_kernel<<<K1_NB, 256, 0, stream>>>(x, W, out);
    epilogue_kernel<<<K2_NB, 64, 0, stream>>>(noise, out, partials);
    finalize_kernel<<<1, 64, 0, stream>>>(partials, out);
}

// Round 6
// 35.564 us; speedup vs baseline: 3.8842x; 1.0263x over previous
//
#include <hip/hip_runtime.h>
#include <math.h>

#define NEXP 8
#define DIM 1024
#define NTOK 32768            // B*S = 8*4096
#define EPSF 1e-9f

#define K1_NB 1024            // 1024 blocks x 4 waves x 8 tokens = 32768
                              // = exactly 4 blocks/CU x 256 CUs, one round

// ---------------------------------------------------------------------------
// Fused kernel: GEMV + gumbel/softmax/top-2 + loss partials, one pass over x.
// W (32 KB) staged in LDS once per block. Each wave: 4 half-iterations of the
// proven 2-token GEMV (xv[2][4] + acc[2][8] keeps live VGPRs ~90 under the
// __launch_bounds__(256,4) cap of 128 -> 4 blocks/CU, 16 waves/CU). The split
// butterfly leaves lane l with logit(expert l&7) replicated over the eight
// 8-lane groups; lanes 0..15 park each half's 2x8 logits in zlds. After a
// barrier, lanes 0..7 each own one token: epilogue fully in registers
// (identical math to the proven standalone K2), write the 9-float mask row,
// park 16 loss stats in slds; block reduce -> partials[block][16].
// ---------------------------------------------------------------------------
__global__ __launch_bounds__(256, 4) void fused_kernel(
    const float* __restrict__ x, const float* __restrict__ W,
    const float* __restrict__ noise, float* __restrict__ out,
    float* __restrict__ partials)
{
    __shared__ float4 Wlds[NEXP * DIM / 4];   // 2048 float4 = 32 KB
    __shared__ float  zlds[4][8][8];          // per-wave token-major logits, 1 KB
    __shared__ float  slds[4][8][16];         // per-token loss stats, 2 KB

    const int tid  = threadIdx.x;
    const int lane = tid & 63;
    const int wid  = tid >> 6;

    const float4* Wg = (const float4*)W;
    #pragma unroll
    for (int i = 0; i < (NEXP * DIM / 4) / 256; ++i)
        Wlds[tid + i * 256] = Wg[tid + i * 256];
    __syncthreads();

    const int gw = (blockIdx.x << 2) + wid;   // wave id 0..4095
    const int t0 = gw << 3;                   // 8 tokens per wave

    const bool p0 = lane & 1;
    const bool p1 = (lane >> 1) & 1;
    const bool p2 = (lane >> 2) & 1;

    #pragma unroll
    for (int h = 0; h < 4; ++h) {
        const int ta = t0 + h * 2;

        // 8 independent x-loads (2 tokens x 4 chunks)
        float4 xv[2][4];
        #pragma unroll
        for (int j = 0; j < 2; ++j)
            #pragma unroll
            for (int p = 0; p < 4; ++p)
                xv[j][p] = *(const float4*)(x + (size_t)(ta + j) * DIM + p * 256 + (lane << 2));

        float acc[2][NEXP];
        #pragma unroll
        for (int j = 0; j < 2; ++j)
            #pragma unroll
            for (int e = 0; e < NEXP; ++e) acc[j][e] = 0.f;

        #pragma unroll
        for (int p = 0; p < 4; ++p)
            #pragma unroll
            for (int e = 0; e < NEXP; ++e) {
                float4 wv = Wlds[e * 256 + p * 64 + lane];
                #pragma unroll
                for (int j = 0; j < 2; ++j)
                    acc[j][e] += xv[j][p].x * wv.x + xv[j][p].y * wv.y
                               + xv[j][p].z * wv.z + xv[j][p].w * wv.w;
            }

        // split butterfly: 8 partials -> lane owns expert (lane&7)
        float k4[2][4];
        #pragma unroll
        for (int j = 0; j < 2; ++j)
            #pragma unroll
            for (int k = 0; k < 4; ++k) {
                float a = acc[j][2 * k], b = acc[j][2 * k + 1];
                float keep = p0 ? b : a, give = p0 ? a : b;
                k4[j][k] = keep + __shfl_xor(give, 1);
            }
        float k2v[2][2];
        #pragma unroll
        for (int j = 0; j < 2; ++j)
            #pragma unroll
            for (int k = 0; k < 2; ++k) {
                float a = k4[j][2 * k], b = k4[j][2 * k + 1];
                float keep = p1 ? b : a, give = p1 ? a : b;
                k2v[j][k] = keep + __shfl_xor(give, 2);
            }
        float z[2];
        #pragma unroll
        for (int j = 0; j < 2; ++j) {
            float a = k2v[j][0], b = k2v[j][1];
            float keep = p2 ? b : a, give = p2 ? a : b;
            z[j] = keep + __shfl_xor(give, 4);
        }
        #pragma unroll
        for (int j = 0; j < 2; ++j) {
            z[j] += __shfl_xor(z[j], 8);
            z[j] += __shfl_xor(z[j], 16);
            z[j] += __shfl_xor(z[j], 32);
        }

        if (lane < 16)
            zlds[wid][h * 2 + (lane >> 3)][lane & 7] = (lane >> 3) ? z[1] : z[0];
    }

    __syncthreads();   // zlds visible (also separates LDS phases)

    // ---- epilogue: lane j < 8 owns token t0+j, all math in registers ----
    if (lane < 8) {
        const int t = t0 + lane;

        float4 za = *(const float4*)&zlds[wid][lane][0];
        float4 zb = *(const float4*)&zlds[wid][lane][4];
        float zt[NEXP] = {za.x, za.y, za.z, za.w, zb.x, zb.y, zb.z, zb.w};

        float4 n0 = *(const float4*)(noise + (size_t)t * NEXP);
        float4 n1 = *(const float4*)(noise + (size_t)t * NEXP + 4);
        float nv[NEXP] = {n0.x, n0.y, n0.z, n0.w, n1.x, n1.y, n1.z, n1.w};

        #pragma unroll
        for (int e = 0; e < NEXP; ++e)
            zt[e] += -logf(-logf(nv[e] + EPSF) + EPSF);

        float m = zt[0];
        #pragma unroll
        for (int e = 1; e < NEXP; ++e) m = fmaxf(m, zt[e]);

        float sc[NEXP], s = 0.f;
        #pragma unroll
        for (int e = 0; e < NEXP; ++e) { sc[e] = expf(zt[e] - m); s += sc[e]; }
        float inv = 1.0f / s;
        #pragma unroll
        for (int e = 0; e < NEXP; ++e) sc[e] *= inv;

        // top-2 scan (value desc, earliest index wins ties — matches lax.top_k)
        float b1v = sc[0]; int b1i = 0;
        float b2v = -1.f;  int b2i = -1;
        #pragma unroll
        for (int e = 1; e < NEXP; ++e) {
            if (sc[e] > b1v)      { b2v = b1v; b2i = b1i; b1v = sc[e]; b1i = e; }
            else if (sc[e] > b2v) { b2v = sc[e]; b2i = e; }
        }

        out[(size_t)t * 9] = 1.0f;
        #pragma unroll
        for (int e = 0; e < NEXP; ++e)
            out[(size_t)t * 9 + 1 + e] = (e == b1i) ? b1v : (e == b2i) ? b2v : 0.f;

        // loss stats for this token: [0..7] = sc, [8..15] = sc^2
        *(float4*)&slds[wid][lane][0]  = make_float4(sc[0], sc[1], sc[2], sc[3]);
        *(float4*)&slds[wid][lane][4]  = make_float4(sc[4], sc[5], sc[6], sc[7]);
        *(float4*)&slds[wid][lane][8]  = make_float4(sc[0]*sc[0], sc[1]*sc[1], sc[2]*sc[2], sc[3]*sc[3]);
        *(float4*)&slds[wid][lane][12] = make_float4(sc[4]*sc[4], sc[5]*sc[5], sc[6]*sc[6], sc[7]*sc[7]);
    }

    __syncthreads();
    if (tid < 16) {
        float s = 0.f;
        #pragma unroll
        for (int w = 0; w < 4; ++w)
            #pragma unroll
            for (int j = 0; j < 8; ++j)
                s += slds[w][j][tid];
        partials[blockIdx.x * 16 + tid] = s;
    }
}

// ---------------------------------------------------------------------------
// K3: finalize loss at out[NTOK*9] from 1024 x 16 partials. 256 threads:
// (v = tid&15, rg = tid>>4) -> 16 row-groups, each sums 64 rows via 4 ILP
// accumulator chains; LDS reduce across groups; wave-0 shuffle for the final
// sum-of-products (same proven math as before).
// ---------------------------------------------------------------------------
__global__ __launch_bounds__(256) void finalize_kernel(
    const float* __restrict__ partials, float* __restrict__ out)
{
    __shared__ float lds16[16][16];
    const int tid = threadIdx.x;
    const int v = tid & 15, rg = tid >> 4;     // 16 row-groups

    float a4[4] = {0.f, 0.f, 0.f, 0.f};
    #pragma unroll
    for (int i = 0; i < K1_NB / 64; ++i)       // 16 iters x 4 chains = 64 rows
        #pragma unroll
        for (int q = 0; q < 4; ++q)
            a4[q] += partials[((i * 4 + q) * 16 + rg) * 16 + v];
    lds16[rg][v] = (a4[0] + a4[1]) + (a4[2] + a4[3]);

    __syncthreads();
    if (tid < 16) {
        float tot = 0.f;
        #pragma unroll
        for (int g = 0; g < 16; ++g) tot += lds16[g][tid];
        // lanes 0..15 of wave 0 hold totals for the 16 stats
        const float invN = 1.0f / (float)NTOK;
        float partner = __shfl_xor(tot, 8);    // pairs sum <-> sumsq
        float prod = (tot * invN) * (partner * invN);
        prod += __shfl_xor(prod, 1);
        prod += __shfl_xor(prod, 2);
        prod += __shfl_xor(prod, 4);
        if (tid == 0)
            out[(size_t)NTOK * 9] = prod * 64.0f;   // * E^2
    }
}

extern "C" void kernel_launch(void* const* d_in, const int* in_sizes, int n_in,
                              void* d_out, int out_size, void* d_ws, size_t ws_size,
                              hipStream_t stream) {
    const float* x     = (const float*)d_in[0];
    const float* W     = (const float*)d_in[1];
    const float* noise = (const float*)d_in[2];
    float* out = (float*)d_out;
    float* partials = (float*)d_ws;   // 1024*16 floats = 64 KB

    fused_kernel<<<K1_NB, 256, 0, stream>>>(x, W, noise, out, partials);
    finalize_kernel<<<1, 256, 0, stream>>>(partials, out);
}